// Round 7
// baseline (355.468 us; speedup 1.0000x reference)
//
#include <hip/hip_runtime.h>

namespace {
constexpr int I_N   = 512;
constexpr int R_N   = 16384;
constexpr int NTOT  = I_N + R_N;      // 16896
constexpr int ZW    = NTOT;           // permanently-zero state byte (masked neighbors)
constexpr int N_OUT = 10;
constexpr int G     = 248;            // < 256: co-residency slack
constexpr int T     = 1024;
constexpr int UTOT  = NTOT / 8;       // 2112 units of 8 nodes
constexpr int STRIDE = 16960;         // per-group state stride (bytes), 16B aligned
constexpr size_t SBUF = (size_t)8 * STRIDE;

// workspace layout (bytes)
constexpr size_t OFF_ADJ = 0;                              // NTOT*8 u32
constexpr size_t OFF_LUT = OFF_ADJ + (size_t)NTOT * 32;    // NTOT*8 u32
constexpr size_t OFF_WPK = OFF_LUT + (size_t)NTOT * 32;    // 1024 u32
constexpr size_t OFF_XPK = OFF_WPK + 4096;                 // 2048 u32
constexpr size_t OFF_INJ = OFF_XPK + 8192;                 // 8*32*512 u8
constexpr size_t OFF_BAR = OFF_INJ + 131072;               // 4096 u32 = 16KB
constexpr size_t OFF_ST  = OFF_BAR + 16384;                // 2 * 8 * STRIDE

using u64 = unsigned long long;
using u8  = unsigned char;

// prep_all gid segmentation
constexpr int PA_BIG = NTOT * 8;        // adj/lut packing          135168
constexpr int PA_W   = PA_BIG;          // + wpk                    1024
constexpr int PA_X   = PA_W + 1024;     // + xpk2                   2048
constexpr int PA_B   = PA_X + 2048;     // + bar zero               4096
constexpr int PA_S   = PA_B + 4096;     // + state init             8*NTOT
constexpr int PA_TOT = PA_S + 8 * NTOT; // = 277504 = 1084*256
}

// ---- cross-XCD (MALL) atomics: one-time registration only ----
__device__ __forceinline__ unsigned afa_sys(unsigned* p) {
  return __hip_atomic_fetch_add(p, 1u, __ATOMIC_RELAXED, __HIP_MEMORY_SCOPE_SYSTEM);
}
__device__ __forceinline__ unsigned lda_sys(const unsigned* p) {
  return __hip_atomic_load(p, __ATOMIC_RELAXED, __HIP_MEMORY_SCOPE_SYSTEM);
}
__device__ __forceinline__ void sta_sys(unsigned* p, unsigned v) {
  __hip_atomic_store(p, v, __ATOMIC_RELAXED, __HIP_MEMORY_SCOPE_SYSTEM);
}
// ---- XCD-local (L2) sc0 ops for the per-tick barrier ----
__device__ __forceinline__ unsigned ld_l2(const unsigned* p) {
  return __hip_atomic_load(p, __ATOMIC_RELAXED, __HIP_MEMORY_SCOPE_AGENT);
}
__device__ __forceinline__ void st_l2(unsigned* p, unsigned v) {
  __hip_atomic_store(p, v, __ATOMIC_RELAXED, __HIP_MEMORY_SCOPE_AGENT);
}

// ---- fused prep: adj/lut pack + wpk + xpk2 + bar zero + state(n>=512) init ----
__global__ __launch_bounds__(256) void prep_all(
    const int* __restrict__ adj, const int* __restrict__ deg,
    const float* __restrict__ lut, const float* __restrict__ x,
    const float* __restrict__ w_in, const float* __restrict__ init,
    unsigned* __restrict__ adjenc, unsigned* __restrict__ lutpk,
    unsigned* __restrict__ wpk, unsigned* __restrict__ xpk2,
    unsigned* __restrict__ bar, u8* __restrict__ st)
{
  int gid = blockIdx.x * 256 + threadIdx.x;
  if (gid < PA_BIG) {
    int n = gid >> 3, k = gid & 7;
    adjenc[gid] = (k < deg[n]) ? (unsigned)adj[gid] : (unsigned)ZW;
    const float4* lp = reinterpret_cast<const float4*>(lut + (size_t)n * 256 + k * 32);
    unsigned w = 0;
    #pragma unroll
    for (int j = 0; j < 8; ++j) {
      float4 v = lp[j];
      w |= (v.x > 0.5f ? 1u : 0u) << (4 * j + 0);
      w |= (v.y > 0.5f ? 1u : 0u) << (4 * j + 1);
      w |= (v.z > 0.5f ? 1u : 0u) << (4 * j + 2);
      w |= (v.w > 0.5f ? 1u : 0u) << (4 * j + 3);
    }
    lutpk[gid] = w;
  } else if (gid < PA_X) {                // wpk[c*512+i], bit b = w_in[c*32+b][i]
    int i2 = gid - PA_W;
    int c = i2 >> 9, i = i2 & 511;
    unsigned w = 0;
    for (int b = 0; b < 32; ++b)
      w |= (w_in[(c * 32 + b) * 512 + i] > 0.5f ? 1u : 0u) << b;
    wpk[i2] = w;
  } else if (gid < PA_B) {                // j = m*32+s*2+c -> xpk2[(s*2+c)*64+m]
    int j = gid - PA_X;
    const float* xp = x + (size_t)j * 32;
    unsigned w = 0;
    for (int b = 0; b < 32; ++b) w |= (xp[b] > 0.5f ? 1u : 0u) << b;
    xpk2[(j & 31) * 64 + (j >> 5)] = w;
  } else if (gid < PA_S) {
    bar[gid - PA_B] = 0u;                 // registration + arrival words
  } else {
    int j = gid - PA_S;
    int g = j / NTOT;
    int n = j - g * NTOT;
    if (n >= I_N)
      st[(size_t)g * STRIDE + n] = (init[n] > 0.5f) ? (u8)0xFF : (u8)0x00;
    if (n == 0) {
      st[(size_t)g * STRIDE + ZW] = 0;          // buffer A pad
      st[SBUF + (size_t)g * STRIDE + ZW] = 0;   // buffer B pad
    }
  }
}

// ---- prep: inj8[g][sc][n]; sc==0 waves also write buffer-A state for n<512 ----
__global__ __launch_bounds__(256) void inj_pack(
    const unsigned* __restrict__ wpk, const unsigned* __restrict__ xpk2,
    const float* __restrict__ init, u8* __restrict__ inj8, u8* __restrict__ st)
{
  int wv = (blockIdx.x * 256 + threadIdx.x) >> 6;   // 0..255
  int lane = threadIdx.x & 63;
  int g = wv >> 5, sc = wv & 31, c = sc & 1, b = lane & 7;
  unsigned xw = xpk2[sc * 64 + g * 8 + b];
  for (int it = 0; it < 64; ++it) {
    int nbase = it * 8, n = nbase + (lane >> 3);
    unsigned wb = wpk[c * 512 + n];
    u64 bb = __ballot((__popc(xw & wb) & 1) != 0);
    if (sc == 0) {
      u64 ib = __ballot(init[n] > 0.5f);
      if (lane == 0)
        *(u64*)(st + (size_t)g * STRIDE + nbase) = ib ^ bb;
    }
    if (lane == 0)
      *(u64*)(inj8 + ((size_t)(g * 32 + sc) << 9) + nbase) = bb;
  }
}

// ---- per-XCD barrier: store-own-slot + distributed vector poll (no atomics) ----
// arrival slot words at bar[512 + g*256 + slot*4] (16B padding per slot)
__device__ __forceinline__ void xcd_barrier(unsigned* bar, int g, unsigned kcnt,
                                            int slot, unsigned p)
{
  __syncthreads();   // per-wave vmcnt(0): this block's state stores are in L2
  const int tid = threadIdx.x;
  if (tid < 64) {
    unsigned* base = bar + 512 + g * 256;
    if (tid == 0) st_l2(base + slot * 4, p);        // announce arrival (sc0 store)
    unsigned l = ((unsigned)tid < kcnt) ? (unsigned)tid : 0u;
    const unsigned* pw = base + l * 4;
    unsigned v;
    do { v = ld_l2(pw); } while (__ballot(v < p) != 0ull);
  }
  __syncthreads();
}

// ---- main: LDS mirror; asm-batched LDS gathers; distributed-poll L2 barrier ----
__global__ __launch_bounds__(1024) void reservoir_main(
    const unsigned* __restrict__ adjenc, const unsigned* __restrict__ lutpk,
    const u8* __restrict__ inj8, u8* __restrict__ st, unsigned* __restrict__ bar)
{
  extern __shared__ char dynpad[];           // occupancy pin -> 1 block/CU
  (void)dynpad;
  __shared__ __align__(16) u8 sstate[STRIDE];
  __shared__ int s_grp, s_slot, s_cnt;
  const int tid = threadIdx.x;
  const int lane = tid & 63;
  const int wv16 = tid >> 6;

  // --- self-organize by physical XCD (one-time, MALL-scope) ---
  if (tid == 0) {
    unsigned xcc;
    asm volatile("s_getreg_b32 %0, hwreg(HW_REG_XCC_ID)" : "=s"(xcc));
    int g = (int)(xcc & 7u);
    s_grp = g;
    s_slot = (int)afa_sys(&bar[32 + g * 16]);
    asm volatile("s_waitcnt vmcnt(0)" ::: "memory");  // reg-add lands BEFORE count
    unsigned r = afa_sys(&bar[0]);
    if (r == (unsigned)(G - 1)) sta_sys(&bar[16], 1u);
    while (lda_sys(&bar[16]) < 1u) __builtin_amdgcn_s_sleep(2);
    s_cnt = (int)lda_sys(&bar[32 + g * 16]);
  }
  __syncthreads();
  const int g = s_grp;
  const unsigned kcnt = (unsigned)s_cnt;
  const int slot = s_slot;
  const unsigned u0 = (unsigned)(((u64)slot * UTOT) / kcnt);
  const unsigned u1 = (unsigned)(((u64)(slot + 1) * UTOT) / kcnt);

  u8* bA = st + (size_t)g * STRIDE;
  u8* bB = st + SBUF + (size_t)g * STRIDE;
  const unsigned bv = (unsigned)(lane & 7);
  const unsigned sb = (unsigned)(size_t)&sstate[0];   // LDS byte offset of mirror

  for (int tt = 0; tt < 64; ++tt) {
    const u8* srcg = (tt & 1) ? bB : bA;
    u8*       dstg = (tt & 1) ? bA : bB;

    // --- refresh LDS mirror from local L2 (sc0: bypass stale L1) ---
    {
      uint4 v0, v1;
      const u8* p0 = srcg + tid * 16;
      asm volatile("global_load_dwordx4 %0, %1, off sc0" : "=v"(v0) : "v"(p0));
      const bool tail = tid < (STRIDE - 16384) / 16;   // 36 threads
      const u8* p1 = srcg + 16384 + tid * 16;
      if (tail)
        asm volatile("global_load_dwordx4 %0, %1, off sc0" : "=v"(v1) : "v"(p1));
      asm volatile("s_waitcnt vmcnt(0)" ::: "memory");
      *reinterpret_cast<uint4*>(&sstate[tid * 16]) = v0;
      if (tail) *reinterpret_cast<uint4*>(&sstate[16384 + tid * 16]) = v1;
    }
    __syncthreads();

    const bool injNow = (tt & 1) && (tt < 63);
    const u8* injp = inj8 + ((size_t)(g * 32 + ((tt + 1) >> 1)) << 9);

    for (unsigned u = u0 + wv16; u < u1; u += 16) {
      const int nbase = (int)(u << 3);
      const int n = nbase + (lane >> 3);
      const uint4* ap = reinterpret_cast<const uint4*>(adjenc + ((size_t)n << 3));
      uint4 A = ap[0], B = ap[1];
      // 8 concurrent LDS byte gathers, one wait (forces 8 outstanding: ILP)
      unsigned c0, c1, c2, c3, c4, c5, c6, c7;
      asm volatile(
        "ds_read_u8 %0, %8\n\t"
        "ds_read_u8 %1, %9\n\t"
        "ds_read_u8 %2, %10\n\t"
        "ds_read_u8 %3, %11\n\t"
        "ds_read_u8 %4, %12\n\t"
        "ds_read_u8 %5, %13\n\t"
        "ds_read_u8 %6, %14\n\t"
        "ds_read_u8 %7, %15\n\t"
        "s_waitcnt lgkmcnt(0)"
        : "=&v"(c0), "=&v"(c1), "=&v"(c2), "=&v"(c3),
          "=&v"(c4), "=&v"(c5), "=&v"(c6), "=&v"(c7)
        : "v"(sb + A.x), "v"(sb + A.y), "v"(sb + A.z), "v"(sb + A.w),
          "v"(sb + B.x), "v"(sb + B.y), "v"(sb + B.z), "v"(sb + B.w));
      unsigned idx;
      idx  = ((c0 >> bv) & 1u) << 7;
      idx |= ((c1 >> bv) & 1u) << 6;
      idx |= ((c2 >> bv) & 1u) << 5;
      idx |= ((c3 >> bv) & 1u) << 4;
      idx |= ((c4 >> bv) & 1u) << 3;
      idx |= ((c5 >> bv) & 1u) << 2;
      idx |= ((c6 >> bv) & 1u) << 1;
      idx |= ((c7 >> bv) & 1u);
      unsigned lv  = lutpk[((size_t)n << 3) + (idx >> 5)];
      unsigned bit = (lv >> (idx & 31u)) & 1u;
      u64 bb = __ballot(bit != 0);
      if (lane == 0) {
        if (injNow && nbase < I_N) bb ^= *(const u64*)(injp + nbase);
        *(u64*)(dstg + nbase) = bb;   // plain store -> my XCD's L2
      }
    }
    if (tt < 63) xcd_barrier(bar, g, kcnt, slot, (unsigned)(tt + 1));
  }
}

// ---- readout: block m = batch (g=m>>3, bit=m&7); final state in buffer A ----
__global__ __launch_bounds__(512) void readout_k(
    const u8* __restrict__ st, const float* __restrict__ Wout,
    const float* __restrict__ bout, float* __restrict__ out)
{
  const int m = blockIdx.x;
  const int gg = m >> 3, b = m & 7;
  const int lane = threadIdx.x & 63;
  const u8* sp = st + (size_t)gg * STRIDE + I_N;
  float acc[N_OUT];
  #pragma unroll
  for (int o = 0; o < N_OUT; ++o) acc[o] = 0.f;
  for (int r = threadIdx.x; r < R_N; r += 512) {
    float bf = (float)((sp[r] >> b) & 1u);
    #pragma unroll
    for (int o = 0; o < N_OUT; ++o)
      acc[o] += bf * Wout[(size_t)o * R_N + r];
  }
  #pragma unroll
  for (int o = 0; o < N_OUT; ++o)
    for (int off = 32; off > 0; off >>= 1)
      acc[o] += __shfl_down(acc[o], off);
  __shared__ float red[8][N_OUT];
  if (lane == 0) {
    int w8 = threadIdx.x >> 6;
    #pragma unroll
    for (int o = 0; o < N_OUT; ++o) red[w8][o] = acc[o];
  }
  __syncthreads();
  if (threadIdx.x < N_OUT) {
    float v = bout[threadIdx.x];
    for (int w8 = 0; w8 < 8; ++w8) v += red[w8][threadIdx.x];
    out[m * N_OUT + threadIdx.x] = 1.0f / (1.0f + expf(-v));
  }
}

extern "C" void kernel_launch(void* const* d_in, const int* in_sizes, int n_in,
                              void* d_out, int out_size, void* d_ws, size_t ws_size,
                              hipStream_t stream)
{
  const float* x    = (const float*)d_in[0];
  const float* w_in = (const float*)d_in[1];
  const int*   adj  = (const int*)d_in[2];
  const int*   deg  = (const int*)d_in[4];
  const float* lut  = (const float*)d_in[5];
  const float* init = (const float*)d_in[7];
  const float* Wout = (const float*)d_in[8];
  const float* bout = (const float*)d_in[9];

  char* ws = (char*)d_ws;
  unsigned* adjenc = (unsigned*)(ws + OFF_ADJ);
  unsigned* lutpk  = (unsigned*)(ws + OFF_LUT);
  unsigned* wpk    = (unsigned*)(ws + OFF_WPK);
  unsigned* xpk2   = (unsigned*)(ws + OFF_XPK);
  u8*       inj8   = (u8*)(ws + OFF_INJ);
  unsigned* bar    = (unsigned*)(ws + OFF_BAR);
  u8*       st     = (u8*)(ws + OFF_ST);

  hipLaunchKernelGGL(prep_all, dim3(PA_TOT / 256), dim3(256), 0, stream,
                     adj, deg, lut, x, w_in, init, adjenc, lutpk, wpk, xpk2, bar, st);
  hipLaunchKernelGGL(inj_pack, dim3(64), dim3(256), 0, stream,
                     wpk, xpk2, init, inj8, st);
  hipLaunchKernelGGL(reservoir_main, dim3(G), dim3(T), 66560, stream,
                     adjenc, lutpk, inj8, st, bar);
  hipLaunchKernelGGL(readout_k, dim3(64), dim3(512), 0, stream,
                     st, Wout, bout, (float*)d_out);
}

// Round 8
// 197.110 us; speedup vs baseline: 1.8034x; 1.8034x over previous
//
#include <hip/hip_runtime.h>

namespace {
constexpr int I_N   = 512;
constexpr int R_N   = 16384;
constexpr int NTOT  = 16896;
constexpr int ZW    = NTOT;           // permanently-zero mirror byte (masked neighbors)
constexpr int N_OUT = 10;
constexpr int G     = 248;            // < 256: co-residency slack
constexpr int T     = 1024;
constexpr int NCH   = NTOT / 64;      // 264 chunks of 64 nodes

// workspace layout (bytes)
constexpr size_t OFF_ADJ = 0;                        // NTOT*8 u32 = 540672
constexpr size_t OFF_LUT = 540672;                   // NTOT*8 u32 = 540672 (bit-reversed pack)
constexpr size_t OFF_WPK = OFF_LUT + 540672;         // 1024 u32
constexpr size_t OFF_XPK = OFF_WPK + 4096;           // 2048 u32
constexpr size_t OFF_INJ = OFF_XPK + 8192;           // 8*32*512 u8
constexpr size_t OFF_BAR = OFF_INJ + 131072;         // 64KB: registration + flags
constexpr size_t OFF_ST  = OFF_BAR + 65536;          // ring: 4 slots * 8 groups * 16896B

using u64 = unsigned long long;
using u8  = unsigned char;

// prep_all gid segmentation
constexpr int PA_BIG = NTOT * 8;          // adjenc + lutpk        135168
constexpr int PA_W   = PA_BIG;            // + wpk                 1024
constexpr int PA_X   = PA_W + 1024;       // + xpk2                2048
constexpr int PA_B   = PA_X + 2048;       // + bar zero            9216
constexpr int PA_S   = PA_B + 9216;       // + slot0 state n>=512  32768
constexpr int PA_TOT = PA_S + 32768;      // 180224 = 704*256
}

// ---- cross-XCD (MALL) atomics: one-time registration only ----
__device__ __forceinline__ unsigned afa_sys(unsigned* p) {
  return __hip_atomic_fetch_add(p, 1u, __ATOMIC_RELAXED, __HIP_MEMORY_SCOPE_SYSTEM);
}
__device__ __forceinline__ unsigned lda_sys(const unsigned* p) {
  return __hip_atomic_load(p, __ATOMIC_RELAXED, __HIP_MEMORY_SCOPE_SYSTEM);
}
__device__ __forceinline__ void sta_sys(unsigned* p, unsigned v) {
  __hip_atomic_store(p, v, __ATOMIC_RELAXED, __HIP_MEMORY_SCOPE_SYSTEM);
}
// ---- XCD-local (L2) sc0 ops for flags ----
__device__ __forceinline__ unsigned ld_l2(const unsigned* p) {
  return __hip_atomic_load(p, __ATOMIC_RELAXED, __HIP_MEMORY_SCOPE_AGENT);
}
__device__ __forceinline__ void st_l2(unsigned* p, unsigned v) {
  __hip_atomic_store(p, v, __ATOMIC_RELAXED, __HIP_MEMORY_SCOPE_AGENT);
}
__device__ __forceinline__ uint4 ld16_sc0(const void* p) {
  uint4 v;
  asm volatile("global_load_dwordx4 %0, %1, off sc0\n\ts_waitcnt vmcnt(0)"
               : "=v"(v) : "v"(p) : "memory");
  return v;
}
// 8x8 bit-matrix transpose about the main diagonal (bit(8r+c) <-> bit(8c+r))
__device__ __forceinline__ u64 flipDiag(u64 x) {
  u64 t;
  t = 0x0f0f0f0f00000000ull & (x ^ (x << 28)); x ^= t ^ (t >> 28);
  t = 0x3333000033330000ull & (x ^ (x << 14)); x ^= t ^ (t >> 14);
  t = 0x5500550055005500ull & (x ^ (x << 7));  x ^= t ^ (t >> 7);
  return x;
}

// ---- fused prep ----
__global__ __launch_bounds__(256) void prep_all(
    const int* __restrict__ adj, const int* __restrict__ deg,
    const float* __restrict__ lut, const float* __restrict__ x,
    const float* __restrict__ w_in, const float* __restrict__ init,
    unsigned* __restrict__ adjenc, unsigned* __restrict__ lutpk,
    unsigned* __restrict__ wpk, unsigned* __restrict__ xpk2,
    unsigned* __restrict__ bar, u8* __restrict__ st)
{
  int gid = blockIdx.x * 256 + threadIdx.x;
  if (gid < PA_BIG) {
    int n = gid >> 3, w = gid & 7;
    adjenc[gid] = (w < deg[n]) ? (unsigned)adj[gid] : (unsigned)ZW;
    // lutpk word w of node n, bit i = lut[n][bitrev8(w*32+i)]
    const float* row = lut + (size_t)n * 256;
    unsigned word = 0;
    for (int i = 0; i < 32; ++i) {
      unsigned r = __brev((unsigned)(w * 32 + i)) >> 24;
      word |= (row[r] > 0.5f ? 1u : 0u) << i;
    }
    lutpk[gid] = word;
  } else if (gid < PA_X) {                // wpk[c*512+i], bit b = w_in[c*32+b][i]
    int i2 = gid - PA_W;
    int c = i2 >> 9, i = i2 & 511;
    unsigned w = 0;
    for (int b = 0; b < 32; ++b)
      w |= (w_in[(c * 32 + b) * 512 + i] > 0.5f ? 1u : 0u) << b;
    wpk[i2] = w;
  } else if (gid < PA_B) {                // j = m*32+s*2+c -> xpk2[(s*2+c)*64+m]
    int j = gid - PA_X;
    const float* xp = x + (size_t)j * 32;
    unsigned w = 0;
    for (int b = 0; b < 32; ++b) w |= (xp[b] > 0.5f ? 1u : 0u) << b;
    xpk2[(j & 31) * 64 + (j >> 5)] = w;
  } else if (gid < PA_S) {
    bar[gid - PA_B] = 0u;                 // registration words + flags
  } else {
    int j = gid - PA_S;                   // slot0 state for n>=512, u32-packed
    int g = j >> 12, i = j & 4095;
    int n = I_N + i * 4;
    unsigned v = 0;
    #pragma unroll
    for (int b = 0; b < 4; ++b)
      v |= (init[n + b] > 0.5f ? 0xFFu : 0x00u) << (8 * b);
    *(unsigned*)(st + (size_t)g * NTOT + n) = v;
  }
}

// ---- prep: inj8[g][sc][n] bytes; sc==0 threads also write slot0 state for n<512 ----
__global__ __launch_bounds__(256) void inj_pack(
    const unsigned* __restrict__ wpk, const unsigned* __restrict__ xpk2,
    const float* __restrict__ init, u8* __restrict__ inj8, u8* __restrict__ st)
{
  int gid = blockIdx.x * 256 + threadIdx.x;   // 8*32*512
  int g = gid >> 14, sc = (gid >> 9) & 31, n = gid & 511;
  int c = sc & 1;
  unsigned wb = wpk[c * 512 + n];
  unsigned acc = 0;
  #pragma unroll
  for (int b = 0; b < 8; ++b) {
    unsigned xw = xpk2[sc * 64 + g * 8 + b];
    acc |= (unsigned)(__popc(xw & wb) & 1) << b;
  }
  inj8[gid] = (u8)acc;
  if (sc == 0)
    st[(size_t)g * NTOT + n] = (u8)(((init[n] > 0.5f) ? 0xFFu : 0x00u) ^ acc);
}

// ---- main: per-lane node, bit-transpose, ring-buffer dataflow (no global barrier) ----
__global__ __launch_bounds__(1024) void reservoir_main(
    const unsigned* __restrict__ adjenc, const unsigned* __restrict__ lutpk,
    const u8* __restrict__ inj8, u8* __restrict__ st, unsigned* __restrict__ bar)
{
  extern __shared__ char dynpad[];           // occupancy pin -> 1 block/CU
  (void)dynpad;
  __shared__ __align__(16) u8 sstate[16960]; // mirror (16896) + ZW byte
  __shared__ unsigned lutlds[9216];          // per-lane LUT, 36B stride
  __shared__ int s_grp, s_slot, s_cnt;
  const int tid = threadIdx.x;
  const int lane = tid & 63;

  // --- one-time registration by physical XCD (MALL scope) ---
  if (tid == 0) {
    unsigned xcc;
    asm volatile("s_getreg_b32 %0, hwreg(HW_REG_XCC_ID)" : "=s"(xcc));
    int g = (int)(xcc & 7u);
    s_grp = g;
    s_slot = (int)afa_sys(&bar[32 + g * 16]);
    asm volatile("s_waitcnt vmcnt(0)" ::: "memory");
    unsigned r = afa_sys(&bar[0]);
    if (r == (unsigned)(G - 1)) sta_sys(&bar[16], 1u);
    while (lda_sys(&bar[16]) < 1u) __builtin_amdgcn_s_sleep(2);
    s_cnt = (int)lda_sys(&bar[32 + g * 16]);
  }
  __syncthreads();
  const int g = s_grp;
  const unsigned kcnt = (unsigned)s_cnt;
  const int slot = s_slot;
  const unsigned wpg = kcnt * 16u;                 // waves in my group
  const unsigned wgid = (unsigned)slot * 16u + (unsigned)(tid >> 6);
  // chunk range for this wave: {c : floor(c*wpg/NCH) == wgid}
  const unsigned clo = (wgid * (unsigned)NCH + wpg - 1u) / wpg;
  const unsigned chi = ((wgid + 1u) * (unsigned)NCH + wpg - 1u) / wpg;
  const bool hasC = clo < chi && clo < (unsigned)NCH;

  // preload first chunk: adjacency regs + per-lane LUT into LDS
  int n0 = 0; bool isInj0 = false;
  uint4 A0 = {0,0,0,0}, B0 = {0,0,0,0};
  if (hasC) {
    n0 = (int)(clo * 64u) + lane;
    const uint4* ap = reinterpret_cast<const uint4*>(adjenc + ((size_t)n0 << 3));
    A0 = ap[0]; B0 = ap[1];
    #pragma unroll
    for (int w = 0; w < 8; ++w)
      lutlds[tid * 9 + w] = lutpk[((size_t)n0 << 3) + w];
    isInj0 = n0 < I_N;
  }
  if (tid == 0) *(u64*)&sstate[16896] = 0ull;      // ZW byte(s)

  // per-thread refresh segment -> owning writer-slot (flag index)
  const unsigned sB = (((unsigned)(tid >> 2) * wpg) / (unsigned)NCH) >> 4;
  const unsigned sT = ((((256u + (unsigned)(tid >> 2))) * wpg / (unsigned)NCH)) >> 4;
  unsigned* flags = bar + 1024;                    // flag(g,s) at [ (g*64+s)*16 ]
  const unsigned* fB = flags + ((unsigned)g * 64u + sB) * 16u;
  const unsigned* fT = flags + ((unsigned)g * 64u + sT) * 16u;
  unsigned* fMy = flags + ((unsigned)g * 64u + (unsigned)slot) * 16u;

  u8* gbase = st + (size_t)g * NTOT;               // + slot*8*NTOT per ring slot

  for (int tt = 1; tt <= 64; ++tt) {
    const u8* src = gbase + (size_t)((tt - 1) & 3) * (8 * NTOT);
    u8*       dst = gbase + (size_t)(tt & 3) * (8 * NTOT);

    // --- refresh mirror from ring slot, gated by owning block's flag ---
    {
      unsigned need = (unsigned)(tt - 1);
      unsigned f;
      do { f = ld_l2(fB); } while (f < need);
      uint4 v = ld16_sc0(src + tid * 16);
      *reinterpret_cast<uint4*>(&sstate[tid * 16]) = v;
      if (tid < 32) {
        do { f = ld_l2(fT); } while (f < need);
        uint4 v2 = ld16_sc0(src + 16384 + tid * 16);
        *reinterpret_cast<uint4*>(&sstate[16384 + tid * 16]) = v2;
      }
    }
    __syncthreads();

    // --- compute: one node per lane ---
    if (hasC) {
      unsigned b0 = sstate[A0.x], b1 = sstate[A0.y];
      unsigned b2 = sstate[A0.z], b3 = sstate[A0.w];
      unsigned b4 = sstate[B0.x], b5 = sstate[B0.y];
      unsigned b6 = sstate[B0.z], b7 = sstate[B0.w];
      unsigned lo = b0 | (b1 << 8) | (b2 << 16) | (b3 << 24);
      unsigned hi = b4 | (b5 << 8) | (b6 << 16) | (b7 << 24);
      u64 y = flipDiag(((u64)hi << 32) | lo);
      unsigned out = 0;
      #pragma unroll
      for (int j = 0; j < 8; ++j) {
        unsigned idx = (unsigned)(y >> (8 * j)) & 255u;
        unsigned w = lutlds[tid * 9 + (idx >> 5)];
        out |= ((w >> (idx & 31u)) & 1u) << j;
      }
      if (isInj0 && (tt & 1) == 0 && tt < 64)
        out ^= inj8[(size_t)(g * 32 + (tt >> 1)) * 512 + n0];
      dst[n0] = (u8)out;
      // rare fallback: extra chunks (only when a group got < 17 blocks)
      for (unsigned c = clo + 1; c < chi && c < (unsigned)NCH; ++c) {
        int n = (int)(c * 64u) + lane;
        const uint4* ap = reinterpret_cast<const uint4*>(adjenc + ((size_t)n << 3));
        uint4 A = ap[0], B = ap[1];
        unsigned d0 = sstate[A.x], d1 = sstate[A.y], d2 = sstate[A.z], d3 = sstate[A.w];
        unsigned d4 = sstate[B.x], d5 = sstate[B.y], d6 = sstate[B.z], d7 = sstate[B.w];
        unsigned l2 = d0 | (d1 << 8) | (d2 << 16) | (d3 << 24);
        unsigned h2 = d4 | (d5 << 8) | (d6 << 16) | (d7 << 24);
        u64 y2 = flipDiag(((u64)h2 << 32) | l2);
        unsigned o2 = 0;
        #pragma unroll
        for (int j = 0; j < 8; ++j) {
          unsigned idx = (unsigned)(y2 >> (8 * j)) & 255u;
          unsigned w = lutpk[((size_t)n << 3) + (idx >> 5)];
          o2 |= ((w >> (idx & 31u)) & 1u) << j;
        }
        if (n < I_N && (tt & 1) == 0 && tt < 64)
          o2 ^= inj8[(size_t)(g * 32 + (tt >> 1)) * 512 + n];
        dst[n] = (u8)o2;
      }
    }
    __syncthreads();   // drains stores (vmcnt 0) + protects mirror from next refresh
    if (tid == 0) st_l2(fMy, (unsigned)tt);        // my share of tick tt is in L2
  }
}

// ---- readout: block m = batch (g=m>>3, bit=m&7); final state in ring slot 0 ----
__global__ __launch_bounds__(512) void readout_k(
    const u8* __restrict__ st, const float* __restrict__ Wout,
    const float* __restrict__ bout, float* __restrict__ out)
{
  const int m = blockIdx.x;
  const int gg = m >> 3, b = m & 7;
  const int lane = threadIdx.x & 63;
  const u8* sp = st + (size_t)gg * NTOT + I_N;     // slot 0 plane
  float acc[N_OUT];
  #pragma unroll
  for (int o = 0; o < N_OUT; ++o) acc[o] = 0.f;
  for (int r = threadIdx.x; r < R_N; r += 512) {
    float bf = (float)((sp[r] >> b) & 1u);
    #pragma unroll
    for (int o = 0; o < N_OUT; ++o)
      acc[o] += bf * Wout[(size_t)o * R_N + r];
  }
  #pragma unroll
  for (int o = 0; o < N_OUT; ++o)
    for (int off = 32; off > 0; off >>= 1)
      acc[o] += __shfl_down(acc[o], off);
  __shared__ float red[8][N_OUT];
  if (lane == 0) {
    int w8 = threadIdx.x >> 6;
    #pragma unroll
    for (int o = 0; o < N_OUT; ++o) red[w8][o] = acc[o];
  }
  __syncthreads();
  if (threadIdx.x < N_OUT) {
    float v = bout[threadIdx.x];
    for (int w8 = 0; w8 < 8; ++w8) v += red[w8][threadIdx.x];
    out[m * N_OUT + threadIdx.x] = 1.0f / (1.0f + expf(-v));
  }
}

extern "C" void kernel_launch(void* const* d_in, const int* in_sizes, int n_in,
                              void* d_out, int out_size, void* d_ws, size_t ws_size,
                              hipStream_t stream)
{
  const float* x    = (const float*)d_in[0];
  const float* w_in = (const float*)d_in[1];
  const int*   adj  = (const int*)d_in[2];
  const int*   deg  = (const int*)d_in[4];
  const float* lut  = (const float*)d_in[5];
  const float* init = (const float*)d_in[7];
  const float* Wout = (const float*)d_in[8];
  const float* bout = (const float*)d_in[9];

  char* ws = (char*)d_ws;
  unsigned* adjenc = (unsigned*)(ws + OFF_ADJ);
  unsigned* lutpk  = (unsigned*)(ws + OFF_LUT);
  unsigned* wpk    = (unsigned*)(ws + OFF_WPK);
  unsigned* xpk2   = (unsigned*)(ws + OFF_XPK);
  u8*       inj8   = (u8*)(ws + OFF_INJ);
  unsigned* bar    = (unsigned*)(ws + OFF_BAR);
  u8*       st     = (u8*)(ws + OFF_ST);

  hipLaunchKernelGGL(prep_all, dim3(PA_TOT / 256), dim3(256), 0, stream,
                     adj, deg, lut, x, w_in, init, adjenc, lutpk, wpk, xpk2, bar, st);
  hipLaunchKernelGGL(inj_pack, dim3(512), dim3(256), 0, stream,
                     wpk, xpk2, init, inj8, st);
  hipLaunchKernelGGL(reservoir_main, dim3(G), dim3(T), 40960, stream,
                     adjenc, lutpk, inj8, st, bar);
  hipLaunchKernelGGL(readout_k, dim3(64), dim3(512), 0, stream,
                     st, Wout, bout, (float*)d_out);
}

// Round 9
// 181.693 us; speedup vs baseline: 1.9564x; 1.0849x over previous
//
#include <hip/hip_runtime.h>

namespace {
constexpr int I_N   = 512;
constexpr int R_N   = 16384;
constexpr int NTOT  = 16896;
constexpr int ZW    = NTOT;           // permanently-zero mirror byte (masked neighbors)
constexpr int N_OUT = 10;
constexpr int G     = 248;            // < 256: co-residency slack
constexpr int T     = 1024;
constexpr int NCH   = NTOT / 64;      // 264 chunks of 64 nodes

// workspace layout (bytes)
constexpr size_t OFF_ADJ = 0;                        // NTOT*8 u32 = 540672
constexpr size_t OFF_LUT = 540672;                   // NTOT*8 u32 = 540672 (bit-reversed pack)
constexpr size_t OFF_WPK = OFF_LUT + 540672;         // 1024 u32
constexpr size_t OFF_XPK = OFF_WPK + 4096;           // 2048 u32
constexpr size_t OFF_INJ = OFF_XPK + 8192;           // 8*32*512 u8
constexpr size_t OFF_BAR = OFF_INJ + 131072;         // 64KB: registration + flags
constexpr size_t OFF_ST  = OFF_BAR + 65536;          // ring: 4 slots * 8 groups * 16896B

using u64 = unsigned long long;
using u8  = unsigned char;

// prep_all gid segmentation
constexpr int PA_BIG = NTOT * 8;          // adjenc + lutpk        135168
constexpr int PA_W   = PA_BIG;            // + wpk                 1024
constexpr int PA_X   = PA_W + 1024;       // + xpk2                2048
constexpr int PA_B   = PA_X + 2048;       // + bar zero            9216
constexpr int PA_S   = PA_B + 9216;       // + slot0 state n>=512  32768
constexpr int PA_TOT = PA_S + 32768;      // 180224 = 704*256
}

// ---- cross-XCD (MALL) atomics: one-time registration only ----
__device__ __forceinline__ unsigned afa_sys(unsigned* p) {
  return __hip_atomic_fetch_add(p, 1u, __ATOMIC_RELAXED, __HIP_MEMORY_SCOPE_SYSTEM);
}
__device__ __forceinline__ unsigned lda_sys(const unsigned* p) {
  return __hip_atomic_load(p, __ATOMIC_RELAXED, __HIP_MEMORY_SCOPE_SYSTEM);
}
__device__ __forceinline__ void sta_sys(unsigned* p, unsigned v) {
  __hip_atomic_store(p, v, __ATOMIC_RELAXED, __HIP_MEMORY_SCOPE_SYSTEM);
}
// ---- XCD-local (L2) sc0 ops for flags ----
__device__ __forceinline__ unsigned ld_l2(const unsigned* p) {
  return __hip_atomic_load(p, __ATOMIC_RELAXED, __HIP_MEMORY_SCOPE_AGENT);
}
__device__ __forceinline__ void st_l2(unsigned* p, unsigned v) {
  __hip_atomic_store(p, v, __ATOMIC_RELAXED, __HIP_MEMORY_SCOPE_AGENT);
}
__device__ __forceinline__ uint4 ld16_sc0(const void* p) {
  uint4 v;
  asm volatile("global_load_dwordx4 %0, %1, off sc0\n\ts_waitcnt vmcnt(0)"
               : "=v"(v) : "v"(p) : "memory");
  return v;
}
// 8x8 bit-matrix transpose about the main diagonal (bit(8r+c) <-> bit(8c+r))
__device__ __forceinline__ u64 flipDiag(u64 x) {
  u64 t;
  t = 0x0f0f0f0f00000000ull & (x ^ (x << 28)); x ^= t ^ (t >> 28);
  t = 0x3333000033330000ull & (x ^ (x << 14)); x ^= t ^ (t >> 14);
  t = 0x5500550055005500ull & (x ^ (x << 7));  x ^= t ^ (t >> 7);
  return x;
}

// ---- fused prep ----
__global__ __launch_bounds__(256) void prep_all(
    const int* __restrict__ adj, const int* __restrict__ deg,
    const float* __restrict__ lut, const float* __restrict__ x,
    const float* __restrict__ w_in, const float* __restrict__ init,
    unsigned* __restrict__ adjenc, unsigned* __restrict__ lutpk,
    unsigned* __restrict__ wpk, unsigned* __restrict__ xpk2,
    unsigned* __restrict__ bar, u8* __restrict__ st)
{
  int gid = blockIdx.x * 256 + threadIdx.x;
  if (gid < PA_BIG) {
    int n = gid >> 3, w = gid & 7;
    adjenc[gid] = (w < deg[n]) ? (unsigned)adj[gid] : (unsigned)ZW;
    // lutpk word w of node n, bit i = lut[n][bitrev8(w*32+i)]
    const float* row = lut + (size_t)n * 256;
    unsigned word = 0;
    for (int i = 0; i < 32; ++i) {
      unsigned r = __brev((unsigned)(w * 32 + i)) >> 24;
      word |= (row[r] > 0.5f ? 1u : 0u) << i;
    }
    lutpk[gid] = word;
  } else if (gid < PA_X) {                // wpk[c*512+i], bit b = w_in[c*32+b][i]
    int i2 = gid - PA_W;
    int c = i2 >> 9, i = i2 & 511;
    unsigned w = 0;
    for (int b = 0; b < 32; ++b)
      w |= (w_in[(c * 32 + b) * 512 + i] > 0.5f ? 1u : 0u) << b;
    wpk[i2] = w;
  } else if (gid < PA_B) {                // j = m*32+s*2+c -> xpk2[(s*2+c)*64+m]
    int j = gid - PA_X;
    const float* xp = x + (size_t)j * 32;
    unsigned w = 0;
    for (int b = 0; b < 32; ++b) w |= (xp[b] > 0.5f ? 1u : 0u) << b;
    xpk2[(j & 31) * 64 + (j >> 5)] = w;
  } else if (gid < PA_S) {
    bar[gid - PA_B] = 0u;                 // registration words + flags
  } else {
    int j = gid - PA_S;                   // slot0 state for n>=512, u32-packed
    int g = j >> 12, i = j & 4095;
    int n = I_N + i * 4;
    unsigned v = 0;
    #pragma unroll
    for (int b = 0; b < 4; ++b)
      v |= (init[n + b] > 0.5f ? 0xFFu : 0x00u) << (8 * b);
    *(unsigned*)(st + (size_t)g * NTOT + n) = v;
  }
}

// ---- prep: inj8[g][sc][n] bytes; sc==0 threads also write slot0 state for n<512 ----
__global__ __launch_bounds__(256) void inj_pack(
    const unsigned* __restrict__ wpk, const unsigned* __restrict__ xpk2,
    const float* __restrict__ init, u8* __restrict__ inj8, u8* __restrict__ st)
{
  int gid = blockIdx.x * 256 + threadIdx.x;   // 8*32*512
  int g = gid >> 14, sc = (gid >> 9) & 31, n = gid & 511;
  int c = sc & 1;
  unsigned wb = wpk[c * 512 + n];
  unsigned acc = 0;
  #pragma unroll
  for (int b = 0; b < 8; ++b) {
    unsigned xw = xpk2[sc * 64 + g * 8 + b];
    acc |= (unsigned)(__popc(xw & wb) & 1) << b;
  }
  inj8[gid] = (u8)acc;
  if (sc == 0)
    st[(size_t)g * NTOT + n] = (u8)(((init[n] > 0.5f) ? 0xFFu : 0x00u) ^ acc);
}

// ---- main: per-lane node, bit-transpose, single-wave poll-all dataflow ----
__global__ __launch_bounds__(1024) void reservoir_main(
    const unsigned* __restrict__ adjenc, const unsigned* __restrict__ lutpk,
    const u8* __restrict__ inj8, u8* __restrict__ st, unsigned* __restrict__ bar)
{
  extern __shared__ char dynpad[];           // occupancy pin -> 1 block/CU
  (void)dynpad;
  __shared__ __align__(16) u8 sstate[16960]; // mirror (16896) + ZW byte
  __shared__ unsigned lutlds[9216];          // per-lane LUT, 36B stride
  __shared__ int s_grp, s_slot, s_cnt;
  const int tid = threadIdx.x;
  const int lane = tid & 63;

  // --- one-time registration by physical XCD (MALL scope) ---
  if (tid == 0) {
    unsigned xcc;
    asm volatile("s_getreg_b32 %0, hwreg(HW_REG_XCC_ID)" : "=s"(xcc));
    int g = (int)(xcc & 7u);
    s_grp = g;
    s_slot = (int)afa_sys(&bar[32 + g * 16]);
    asm volatile("s_waitcnt vmcnt(0)" ::: "memory");
    unsigned r = afa_sys(&bar[0]);
    if (r == (unsigned)(G - 1)) sta_sys(&bar[16], 1u);
    while (lda_sys(&bar[16]) < 1u) __builtin_amdgcn_s_sleep(2);
    s_cnt = (int)lda_sys(&bar[32 + g * 16]);
  }
  __syncthreads();
  const int g = s_grp;
  const unsigned kcnt = (unsigned)s_cnt;
  const int slot = s_slot;
  const unsigned wpg = kcnt * 16u;                 // waves in my group
  const unsigned wgid = (unsigned)slot * 16u + (unsigned)(tid >> 6);
  // chunk range for this wave: {c : floor(c*wpg/NCH) == wgid}
  const unsigned clo = (wgid * (unsigned)NCH + wpg - 1u) / wpg;
  const unsigned chi = ((wgid + 1u) * (unsigned)NCH + wpg - 1u) / wpg;
  const bool hasC = clo < chi && clo < (unsigned)NCH;

  // preload first chunk: adjacency regs + per-lane LUT into LDS
  int n0 = 0; bool isInj0 = false;
  uint4 A0 = {0,0,0,0}, B0 = {0,0,0,0};
  if (hasC) {
    n0 = (int)(clo * 64u) + lane;
    const uint4* ap = reinterpret_cast<const uint4*>(adjenc + ((size_t)n0 << 3));
    A0 = ap[0]; B0 = ap[1];
    #pragma unroll
    for (int w = 0; w < 8; ++w)
      lutlds[tid * 9 + w] = lutpk[((size_t)n0 << 3) + w];
    isInj0 = n0 < I_N;
  }
  if (tid == 0) *(u64*)&sstate[16896] = 0ull;      // ZW byte(s)

  // flags: 4B stride per slot, one compact region per group (2 cache lines)
  unsigned* flags = bar + 1024;                    // flag(g,s) at [g*64 + s]
  unsigned* fMy   = flags + (unsigned)g * 64u + (unsigned)slot;
  const unsigned lown = ((unsigned)lane < kcnt) ? (unsigned)lane : 0u;
  const unsigned* fPoll = flags + (unsigned)g * 64u + lown;

  u8* gbase = st + (size_t)g * NTOT;               // + slot*8*NTOT per ring slot

  for (int tt = 1; tt <= 64; ++tt) {
    const u8* src = gbase + (size_t)((tt - 1) & 3) * (8 * NTOT);
    u8*       dst = gbase + (size_t)(tt & 3) * (8 * NTOT);

    // --- (a) wave 0 polls ALL owner flags >= tt-1 (2 cache lines total) ---
    if (tid < 64) {
      const unsigned need = (unsigned)(tt - 1);
      unsigned v;
      do { v = ld_l2(fPoll); } while (__ballot(v < need) != 0ull);
    }
    __syncthreads();

    // --- (b) coalesced mirror refresh from ring slot ---
    if (tid >= 992) {                               // wave 15 takes the 512B tail
      uint4 v0, v1;
      asm volatile(
        "global_load_dwordx4 %0, %2, off sc0\n\t"
        "global_load_dwordx4 %1, %3, off sc0\n\t"
        "s_waitcnt vmcnt(0)"
        : "=&v"(v0), "=&v"(v1)
        : "v"(src + tid * 16), "v"(src + 16384 + (tid - 992) * 16)
        : "memory");
      *reinterpret_cast<uint4*>(&sstate[tid * 16]) = v0;
      *reinterpret_cast<uint4*>(&sstate[16384 + (tid - 992) * 16]) = v1;
    } else {
      uint4 v0 = ld16_sc0(src + tid * 16);
      *reinterpret_cast<uint4*>(&sstate[tid * 16]) = v0;
    }
    __syncthreads();

    // --- (c) compute: one node per lane ---
    if (hasC) {
      unsigned b0 = sstate[A0.x], b1 = sstate[A0.y];
      unsigned b2 = sstate[A0.z], b3 = sstate[A0.w];
      unsigned b4 = sstate[B0.x], b5 = sstate[B0.y];
      unsigned b6 = sstate[B0.z], b7 = sstate[B0.w];
      unsigned lo = b0 | (b1 << 8) | (b2 << 16) | (b3 << 24);
      unsigned hi = b4 | (b5 << 8) | (b6 << 16) | (b7 << 24);
      u64 y = flipDiag(((u64)hi << 32) | lo);
      unsigned out = 0;
      #pragma unroll
      for (int j = 0; j < 8; ++j) {
        unsigned idx = (unsigned)(y >> (8 * j)) & 255u;
        unsigned w = lutlds[tid * 9 + (idx >> 5)];
        out |= ((w >> (idx & 31u)) & 1u) << j;
      }
      if (isInj0 && (tt & 1) == 0 && tt < 64)
        out ^= inj8[(size_t)(g * 32 + (tt >> 1)) * 512 + n0];
      dst[n0] = (u8)out;
      // rare fallback: extra chunks (only when a group got very few blocks)
      for (unsigned c = clo + 1; c < chi && c < (unsigned)NCH; ++c) {
        int n = (int)(c * 64u) + lane;
        const uint4* ap = reinterpret_cast<const uint4*>(adjenc + ((size_t)n << 3));
        uint4 A = ap[0], B = ap[1];
        unsigned d0 = sstate[A.x], d1 = sstate[A.y], d2 = sstate[A.z], d3 = sstate[A.w];
        unsigned d4 = sstate[B.x], d5 = sstate[B.y], d6 = sstate[B.z], d7 = sstate[B.w];
        unsigned l2 = d0 | (d1 << 8) | (d2 << 16) | (d3 << 24);
        unsigned h2 = d4 | (d5 << 8) | (d6 << 16) | (d7 << 24);
        u64 y2 = flipDiag(((u64)h2 << 32) | l2);
        unsigned o2 = 0;
        #pragma unroll
        for (int j = 0; j < 8; ++j) {
          unsigned idx = (unsigned)(y2 >> (8 * j)) & 255u;
          unsigned w = lutpk[((size_t)n << 3) + (idx >> 5)];
          o2 |= ((w >> (idx & 31u)) & 1u) << j;
        }
        if (n < I_N && (tt & 1) == 0 && tt < 64)
          o2 ^= inj8[(size_t)(g * 32 + (tt >> 1)) * 512 + n];
        dst[n] = (u8)o2;
      }
    }
    __syncthreads();   // drains stores (vmcnt 0) before flag post
    if (tid == 0) st_l2(fMy, (unsigned)tt);        // my share of tick tt is in L2
  }
}

// ---- readout: block m = batch (g=m>>3, bit=m&7); final state in ring slot 0 ----
__global__ __launch_bounds__(512) void readout_k(
    const u8* __restrict__ st, const float* __restrict__ Wout,
    const float* __restrict__ bout, float* __restrict__ out)
{
  const int m = blockIdx.x;
  const int gg = m >> 3, b = m & 7;
  const int lane = threadIdx.x & 63;
  const u8* sp = st + (size_t)gg * NTOT + I_N;     // slot 0 plane
  float acc[N_OUT];
  #pragma unroll
  for (int o = 0; o < N_OUT; ++o) acc[o] = 0.f;
  for (int r = threadIdx.x; r < R_N; r += 512) {
    float bf = (float)((sp[r] >> b) & 1u);
    #pragma unroll
    for (int o = 0; o < N_OUT; ++o)
      acc[o] += bf * Wout[(size_t)o * R_N + r];
  }
  #pragma unroll
  for (int o = 0; o < N_OUT; ++o)
    for (int off = 32; off > 0; off >>= 1)
      acc[o] += __shfl_down(acc[o], off);
  __shared__ float red[8][N_OUT];
  if (lane == 0) {
    int w8 = threadIdx.x >> 6;
    #pragma unroll
    for (int o = 0; o < N_OUT; ++o) red[w8][o] = acc[o];
  }
  __syncthreads();
  if (threadIdx.x < N_OUT) {
    float v = bout[threadIdx.x];
    for (int w8 = 0; w8 < 8; ++w8) v += red[w8][threadIdx.x];
    out[m * N_OUT + threadIdx.x] = 1.0f / (1.0f + expf(-v));
  }
}

extern "C" void kernel_launch(void* const* d_in, const int* in_sizes, int n_in,
                              void* d_out, int out_size, void* d_ws, size_t ws_size,
                              hipStream_t stream)
{
  const float* x    = (const float*)d_in[0];
  const float* w_in = (const float*)d_in[1];
  const int*   adj  = (const int*)d_in[2];
  const int*   deg  = (const int*)d_in[4];
  const float* lut  = (const float*)d_in[5];
  const float* init = (const float*)d_in[7];
  const float* Wout = (const float*)d_in[8];
  const float* bout = (const float*)d_in[9];

  char* ws = (char*)d_ws;
  unsigned* adjenc = (unsigned*)(ws + OFF_ADJ);
  unsigned* lutpk  = (unsigned*)(ws + OFF_LUT);
  unsigned* wpk    = (unsigned*)(ws + OFF_WPK);
  unsigned* xpk2   = (unsigned*)(ws + OFF_XPK);
  u8*       inj8   = (u8*)(ws + OFF_INJ);
  unsigned* bar    = (unsigned*)(ws + OFF_BAR);
  u8*       st     = (u8*)(ws + OFF_ST);

  hipLaunchKernelGGL(prep_all, dim3(PA_TOT / 256), dim3(256), 0, stream,
                     adj, deg, lut, x, w_in, init, adjenc, lutpk, wpk, xpk2, bar, st);
  hipLaunchKernelGGL(inj_pack, dim3(512), dim3(256), 0, stream,
                     wpk, xpk2, init, inj8, st);
  hipLaunchKernelGGL(reservoir_main, dim3(G), dim3(T), 40960, stream,
                     adjenc, lutpk, inj8, st, bar);
  hipLaunchKernelGGL(readout_k, dim3(64), dim3(512), 0, stream,
                     st, Wout, bout, (float*)d_out);
}